// Round 4
// baseline (534.979 us; speedup 1.0000x reference)
//
#include <hip/hip_runtime.h>

typedef _Float16 f16;
typedef _Float16 f16x2 __attribute__((ext_vector_type(2)));
typedef _Float16 f16x8 __attribute__((ext_vector_type(8)));
typedef float f32x4 __attribute__((ext_vector_type(4)));

#define MFMA16(a,b,c) __builtin_amdgcn_mfma_f32_16x16x32_f16(a,b,c,0,0,0)

#define NITEMS 100000
#define NBLK4  1563   // ceil(100000/64)

// ---- workspace byte offsets ----
#define OFF_WIH   0u
#define OFF_WHH   393216u
#define OFF_MNU   786432u
#define OFF_MNU2  851968u
#define OFF_MNEA  1048576u
#define OFF_MLP1  1081344u
#define OFF_MLP2  1212416u
#define OFF_GI    1409024u          // 12800x768 f16 (column-rotated layout)
#define OFF_TV    21069824u         // 12800x128 f16
#define OFF_MN    24346624u         // 50x256x10x128 f16
#define OFF_YALL  57114624u         // 12800x256 f16
#define OFF_SY    66945024u         // 100000x256 f16
#define OFF_YSUM  118145024u        // 256x256 f32
#define OFF_Y16   118407168u        // 256x256 f16
#define OFF_PMAX  118538240u        // 256x1600 f32
#define OFF_PSUM  120176640u        // 256x1600 f32
#define OFF_LSE   121815040u        // 256 f32

__device__ __forceinline__ float sigm(float x) { return 1.f / (1.f + __expf(-x)); }
// tanh(x) = 1 - 2/(1+exp(2x)); branch-free, saturates correctly at +/-inf
__device__ __forceinline__ float tanh_fast(float x) {
  return 1.f - 2.f / (1.f + __expf(2.f * x));
}
// gi column rotation: bit4 of the within-gate col index moves to bit0
__device__ __forceinline__ int gi_pos(int c) {
  int cg = c & 255;
  return (c & ~255) + ((cg >> 5) << 5) + ((cg & 15) << 1) + ((cg >> 4) & 1);
}

// ============================================================================
// Pack all weight matrices (x @ W.T form) into f16 MFMA B-fragment streams.
// dst[((nt*KS+ks)*64+lane)*8 + j] = W[nt*16 + (lane&15)][ks*32 + (lane>>4)*8 + j]
// ============================================================================
__global__ __launch_bounds__(256) void k_pack(
    const float* s0, const float* s1, const float* s2, const float* s3,
    const float* s4, const float* s5, const float* s6, f16* base)
{
  int fid = blockIdx.x * 256 + threadIdx.x;  // 88064 total
  const float* src; f16* dst; int K, f;
  if (fid < 24576)      { src = s0; dst = base;          K = 256; f = fid; }          // W_ih 768x256
  else if (fid < 49152) { src = s1; dst = base + 196608; K = 256; f = fid - 24576; }  // W_hh 768x256
  else if (fid < 53248) { src = s2; dst = base + 393216; K = 256; f = fid - 49152; }  // MNu_W 128x256
  else if (fid < 65536) { src = s3; dst = base + 425984; K = 384; f = fid - 53248; }  // MNu2_W 256x384
  else if (fid < 67584) { src = s4; dst = base + 524288; K = 128; f = fid - 65536; }  // MNea_W 128x128
  else if (fid < 75776) { src = s5; dst = base + 540672; K = 256; f = fid - 67584; }  // mlp1_W 256x256
  else                  { src = s6; dst = base + 606208; K = 384; f = fid - 75776; }  // mlp2_W 256x384
  int lane = f & 63, t2 = f >> 6, KS = K >> 5;
  int ks = t2 % KS, nt = t2 / KS;
  int row = nt * 16 + (lane & 15), col = ks * 32 + ((lane >> 4) << 3);
  const float* sp = src + (size_t)row * K + col;
  f16x8 v;
  #pragma unroll
  for (int j = 0; j < 8; j++) v[j] = (f16)sp[j];
  *(f16x8*)(dst + (size_t)f * 8) = v;
}

// ============================================================================
// Fused big-parallel GEMMs:
//  blocks 0..399    gi = f16(E[X] @ W_ih.T + b_ih)     (column-rotated layout)
//  blocks 400..799  tv = f16(tanh(KBE[X] @ MNea_W.T + b))
//  blocks 800..3924 Sy = f16(tanh([E|KBE] @ mlp2.T + b)) over 100k items
// ============================================================================
__global__ __launch_bounds__(512) void k_giea_sy(
    const int* __restrict__ X, const float* __restrict__ E,
    const f16* __restrict__ Wih_p, const float* __restrict__ bih, f16* __restrict__ gi,
    const float* __restrict__ KBE, const f16* __restrict__ Wea_p,
    const float* __restrict__ bea, f16* __restrict__ tv,
    const f16* __restrict__ mlp2_p, const float* __restrict__ mlp2b, f16* __restrict__ Sy)
{
  __shared__ __align__(16) char smem[25088];
  int tid = threadIdx.x;
  int w = tid >> 6, lane = tid & 63, lr = lane & 15, lg = lane >> 4;
  if (blockIdx.x < 400) {
    f16 (*At)[264] = (f16(*)[264])smem;
    int r0 = blockIdx.x * 32;         // global row (t*256 + b); one t per block
    int t = r0 >> 8;
    { // stage A-tile (32 rows x 256 K, f32 -> f16), gather with row-0 masking
      int r = tid >> 4, c = (tid & 15) * 16;
      int b = (r0 + r) & 255;
      int item = X[b * 50 + t];
      if (item == 0) {
        #pragma unroll
        for (int j = 0; j < 16; j++) At[r][c + j] = (f16)0.f;
      } else {
        const float4* sp = (const float4*)(E + (size_t)item * 256 + c);
        #pragma unroll
        for (int q = 0; q < 4; q++) {
          float4 v = sp[q];
          At[r][c + q*4 + 0] = (f16)v.x; At[r][c + q*4 + 1] = (f16)v.y;
          At[r][c + q*4 + 2] = (f16)v.z; At[r][c + q*4 + 3] = (f16)v.w;
        }
      }
    }
    __syncthreads();
    f32x4 acc[2][6] = {};
    for (int ks = 0; ks < 8; ks++) {
      f16x8 a0 = *(const f16x8*)(&At[lr][ks * 32 + lg * 8]);
      f16x8 a1 = *(const f16x8*)(&At[16 + lr][ks * 32 + lg * 8]);
      #pragma unroll
      for (int j = 0; j < 6; j++) {
        int nt = w * 6 + j;
        f16x8 bf = *(const f16x8*)(Wih_p + ((size_t)((nt * 8 + ks) * 64 + lane) << 3));
        acc[0][j] = MFMA16(a0, bf, acc[0][j]);
        acc[1][j] = MFMA16(a1, bf, acc[1][j]);
      }
    }
    #pragma unroll
    for (int j = 0; j < 6; j++) {
      int col = (w * 6 + j) * 16 + lr;
      int pos = gi_pos(col);
      float bias = bih[col];
      #pragma unroll
      for (int mt = 0; mt < 2; mt++)
        #pragma unroll
        for (int rr = 0; rr < 4; rr++) {
          int row = r0 + mt * 16 + lg * 4 + rr;
          gi[(size_t)row * 768 + pos] = (f16)(acc[mt][j][rr] + bias);
        }
    }
  } else if (blockIdx.x < 800) {
    f16 (*At)[264] = (f16(*)[264])smem;
    int r0 = (blockIdx.x - 400) * 32;
    int t = r0 >> 8;
    {
      int r = tid >> 4, c = (tid & 15) * 8;
      int b = (r0 + r) & 255;
      int item = X[b * 50 + t];
      if (item == 0) {
        #pragma unroll
        for (int j = 0; j < 8; j++) At[r][c + j] = (f16)0.f;
      } else {
        const float4* sp = (const float4*)(KBE + (size_t)item * 128 + c);
        #pragma unroll
        for (int q = 0; q < 2; q++) {
          float4 v = sp[q];
          At[r][c + q*4 + 0] = (f16)v.x; At[r][c + q*4 + 1] = (f16)v.y;
          At[r][c + q*4 + 2] = (f16)v.z; At[r][c + q*4 + 3] = (f16)v.w;
        }
      }
    }
    __syncthreads();
    f32x4 acc[2] = {};
    for (int ks = 0; ks < 4; ks++) {
      f16x8 a0 = *(const f16x8*)(&At[lr][ks * 32 + lg * 8]);
      f16x8 a1 = *(const f16x8*)(&At[16 + lr][ks * 32 + lg * 8]);
      f16x8 bf = *(const f16x8*)(Wea_p + ((size_t)((w * 4 + ks) * 64 + lane) << 3));
      acc[0] = MFMA16(a0, bf, acc[0]);
      acc[1] = MFMA16(a1, bf, acc[1]);
    }
    int col = w * 16 + lr;
    float bias = bea[col];
    #pragma unroll
    for (int mt = 0; mt < 2; mt++)
      #pragma unroll
      for (int rr = 0; rr < 4; rr++) {
        int row = r0 + mt * 16 + lg * 4 + rr;
        tv[(size_t)row * 128 + col] = (f16)tanh_fast(acc[mt][rr] + bias);
      }
  } else {
    // ---------------- Sy ----------------
    f16* At = (f16*)smem;                      // [32][392]
    int i0 = (blockIdx.x - 800) * 32;
    {
      int r = tid >> 4;
      int item = i0 + r;
      f16* rowp = At + r * 392;
      int cE = (tid & 15) * 16, cK = (tid & 15) * 8;
      if (item == 0) {
        #pragma unroll
        for (int j = 0; j < 16; j++) rowp[cE + j] = (f16)0.f;
        #pragma unroll
        for (int j = 0; j < 8; j++) rowp[256 + cK + j] = (f16)0.f;
      } else {
        const float4* sp = (const float4*)(E + (size_t)item * 256 + cE);
        #pragma unroll
        for (int q = 0; q < 4; q++) {
          float4 v = sp[q];
          rowp[cE + q*4 + 0] = (f16)v.x; rowp[cE + q*4 + 1] = (f16)v.y;
          rowp[cE + q*4 + 2] = (f16)v.z; rowp[cE + q*4 + 3] = (f16)v.w;
        }
        const float4* kp = (const float4*)(KBE + (size_t)item * 128 + cK);
        #pragma unroll
        for (int q = 0; q < 2; q++) {
          float4 v = kp[q];
          rowp[256 + cK + q*4 + 0] = (f16)v.x; rowp[256 + cK + q*4 + 1] = (f16)v.y;
          rowp[256 + cK + q*4 + 2] = (f16)v.z; rowp[256 + cK + q*4 + 3] = (f16)v.w;
        }
      }
    }
    __syncthreads();
    int mt = w & 1, nq = w >> 1;               // 8 waves: 2 m-tiles x 4 nt-quads
    f32x4 acc[4] = {};
    for (int ks = 0; ks < 12; ks++) {
      f16x8 a = *(const f16x8*)(&At[(mt * 16 + lr) * 392 + ks * 32 + lg * 8]);
      #pragma unroll
      for (int j = 0; j < 4; j++) {
        int nt = nq * 4 + j;
        f16x8 bf = *(const f16x8*)(mlp2_p + ((size_t)((nt * 12 + ks) * 64 + lane) << 3));
        acc[j] = MFMA16(a, bf, acc[j]);
      }
    }
    #pragma unroll
    for (int j = 0; j < 4; j++) {
      int col = (nq * 4 + j) * 16 + lr;
      float bias = mlp2b[col];
      #pragma unroll
      for (int rr = 0; rr < 4; rr++) {
        int item = i0 + mt * 16 + lg * 4 + rr;
        Sy[(size_t)item * 256 + col] = (f16)tanh_fast(acc[j][rr] + bias);
      }
    }
  }
}

// ============================================================================
// blocks 0..15   : persistent GRU scan, 16 rows each. W_hh ENTIRELY in VGPRs
//                  (8 waves x 6 tiles x 32B/lane = 192 VGPR/lane), pinned by
//                  an asm anti-remat barrier. Per-step traffic: LDS h only.
// blocks 16..335 : MN trajectory (one wave per (b,f) pair)
// ============================================================================
__global__ __launch_bounds__(512, 2) void k_scan_mn(
    const f16* __restrict__ Whh_p, const float* __restrict__ bhh,
    const f16* __restrict__ gi, f16* __restrict__ y_all,
    const f16* __restrict__ tv, const float* __restrict__ Rm, f16* __restrict__ MN)
{
  __shared__ __align__(16) char smem[16384];
  int tid = threadIdx.x, w = tid >> 6, lane = tid & 63, lr = lane & 15, lg = lane >> 4;

  if (blockIdx.x < 16) {
    f16* hb0 = (f16*)smem;            // [16][256] f16, XOR-swizzled
    f16* hb1 = (f16*)(smem + 8192);
    int r0 = blockIdx.x * 16;
    { float4 z4 = {0.f,0.f,0.f,0.f}; ((float4*)hb0)[tid] = z4; }
    // ---- one-time: load this wave's 6 weight tiles into registers ----
    f16x8 Wr[2][8], Wz[2][8], Wn[2][8];
    #pragma unroll
    for (int p = 0; p < 2; p++) {
      int tr = 2 * w + p;
      #pragma unroll
      for (int ks = 0; ks < 8; ks++) {
        Wr[p][ks] = *(const f16x8*)(Whh_p + ((size_t)(((tr     ) * 8 + ks) * 64 + lane) << 3));
        Wz[p][ks] = *(const f16x8*)(Whh_p + ((size_t)(((16 + tr) * 8 + ks) * 64 + lane) << 3));
        Wn[p][ks] = *(const f16x8*)(Whh_p + ((size_t)(((32 + tr) * 8 + ks) * 64 + lane) << 3));
      }
    }
    // anti-remat: make the loaded values opaque so the compiler cannot
    // re-materialize the global loads inside the t-loop
    #pragma unroll
    for (int p = 0; p < 2; p++)
      #pragma unroll
      for (int ks = 0; ks < 8; ks++)
        asm volatile("" : "+v"(Wr[p][ks]), "+v"(Wz[p][ks]), "+v"(Wn[p][ks]));
    float bR[2], bZ[2], bN[2];
    #pragma unroll
    for (int p = 0; p < 2; p++) {
      int c = w * 32 + p * 16 + lr;
      bR[p] = bhh[c]; bZ[p] = bhh[c + 256]; bN[p] = bhh[c + 512];
    }
    float hreg[2][4] = {};
    const f16* gP = gi + (size_t)(r0 + lg * 4) * 768 + w * 32 + lr * 2;
    // prefetch gi for t=0 (f16x2 = both cols of this lane, rotated layout)
    f16x2 P[4][3];
    #pragma unroll
    for (int rr = 0; rr < 4; rr++)
      #pragma unroll
      for (int g = 0; g < 3; g++)
        P[rr][g] = *(const f16x2*)(gP + rr * 768 + g * 256);
    __syncthreads();
    const f16* hc = hb0; f16* hn_ = hb1;
    int xr = (lr & 7) << 4;
    for (int t = 0; t < 50; t++) {
      // ---- gh = h @ W_hh.T : 48 MFMAs, all operands in regs/LDS ----
      f32x4 aR[2] = {}, aZ[2] = {}, aN[2] = {};
      const char* hbase = (const char*)hc + lr * 512;
      #pragma unroll
      for (int ks = 0; ks < 8; ks++) {
        f16x8 a = *(const f16x8*)(hbase + ((ks * 64 + lg * 16) ^ xr));
        aR[0] = MFMA16(a, Wr[0][ks], aR[0]);
        aR[1] = MFMA16(a, Wr[1][ks], aR[1]);
        aZ[0] = MFMA16(a, Wz[0][ks], aZ[0]);
        aZ[1] = MFMA16(a, Wz[1][ks], aZ[1]);
        aN[0] = MFMA16(a, Wn[0][ks], aN[0]);
        aN[1] = MFMA16(a, Wn[1][ks], aN[1]);
      }
      // ---- GRU elementwise (each lane: 2 cols x 4 rows) ----
      #pragma unroll
      for (int p = 0; p < 2; p++) {
        int col = w * 32 + p * 16 + lr;
        #pragma unroll
        for (int rr = 0; rr < 4; rr++) {
          int row = lg * 4 + rr;
          float rg = sigm((float)P[rr][0][p] + aR[p][rr] + bR[p]);
          float zg = sigm((float)P[rr][1][p] + aZ[p][rr] + bZ[p]);
          float ng = tanh_fast((float)P[rr][2][p] + rg * (aN[p][rr] + bN[p]));
          float hv = ng + zg * (hreg[p][rr] - ng);
          hreg[p][rr] = hv;
          f16 h2 = (f16)hv;
          *(f16*)((char*)hn_ + row * 512 + ((col * 2) ^ ((row & 7) << 4))) = h2;
          y_all[((size_t)t * 256 + r0 + row) * 256 + col] = h2;
        }
      }
      // ---- prefetch gi for t+1 (latency hides under next MFMA phase) ----
      if (t < 49) {
        const f16* gN = gP + (size_t)(t + 1) * 196608;
        #pragma unroll
        for (int rr = 0; rr < 4; rr++)
          #pragma unroll
          for (int g = 0; g < 3; g++)
            P[rr][g] = *(const f16x2*)(gN + rr * 768 + g * 256);
      }
      __syncthreads();
      const f16* tmp = hc; hc = hn_; hn_ = (f16*)tmp;
    }
  } else {
    // ---------------- MN trajectory ----------------
    int pair = (blockIdx.x - 16) * 8 + w;   // 2560 pairs
    int b = pair / 10, f = pair - (pair / 10) * 10;
    float r0_ = Rm[f * 128 + lane], r1_ = Rm[f * 128 + 64 + lane];
    float mn0 = 0.f, mn1 = 0.f;
    for (int t = 0; t < 50; t++) {
      size_t base = ((size_t)t * 256 + b) * 128;
      float ea0 = (float)tv[base + lane] + r0_;
      float ea1 = (float)tv[base + 64 + lane] + r1_;
      float p = mn0 * ea0 + mn1 * ea1;
      #pragma unroll
      for (int off = 32; off > 0; off >>= 1) p += __shfl_xor(p, off);
      float g = sigm(p);
      mn0 += (ea0 - mn0) * g;
      mn1 += (ea1 - mn1) * g;
      size_t mb = (((size_t)t * 256 + b) * 10 + f) * 128;
      MN[mb + lane] = (f16)mn0;
      MN[mb + 64 + lane] = (f16)mn1;
    }
  }
}

// ============================================================================
// Fused per-(t,b)-tile epilogue:
//  U = tanh(y@MNu.T+b); AW = softmax(U@r.T); AC = sum_f AW*MN (kept in LDS);
//  Ut = tanh([y|AC]@MNu2.T+b); y_out = tanh(Ut@mlp1.T+b); ysum += y_out
// ============================================================================
__global__ __launch_bounds__(512) void k_uacut(
    const f16* __restrict__ y_all, const f16* __restrict__ MNu_p,
    const float* __restrict__ MNub, const float* __restrict__ Rm,
    const f16* __restrict__ MN,
    const f16* __restrict__ MNu2_p, const float* __restrict__ MNu2b,
    const f16* __restrict__ mlp1_p, const float* __restrict__ mlp1b,
    float* __restrict__ ysum)
{
  __shared__ __align__(16) f16 Aty[32][264];
  __shared__ float Uf[32][136];
  __shared__ float Lg[32][10];
  __shared__ float Aw[32][10];
  __shared__ __align__(16) f16 ACs[32][136];
  __shared__ __align__(16) f16 Utl[32][264];
  int tid = threadIdx.x, w = tid >> 6, lane = tid & 63, lr = lane & 15, lg = lane >> 4;
  int r0 = blockIdx.x * 32;
  int b0 = r0 & 255;
  {
    int r = tid >> 4, c = (tid & 15) * 16;
    f16x8 v0 = *(const f16x8*)(y_all + (size_t)(r0 + r) * 256 + c);
    f16x8 v1 = *(const f16x8*)(y_all + (size_t)(r0 + r) * 256 + c + 8);
    *(f16x8*)(&Aty[r][c]) = v0;
    *(f16x8*)(&Aty[r][c + 8]) = v1;
  }
  __syncthreads();
  // ---- U = tanh(y @ MNu.T + b) ----
  {
    f32x4 acc[2] = {};
    for (int ks = 0; ks < 8; ks++) {
      f16x8 a0 = *(const f16x8*)(&Aty[lr][ks * 32 + lg * 8]);
      f16x8 a1 = *(const f16x8*)(&Aty[16 + lr][ks * 32 + lg * 8]);
      f16x8 bf = *(const f16x8*)(MNu_p + ((size_t)((w * 8 + ks) * 64 + lane) << 3));
      acc[0] = MFMA16(a0, bf, acc[0]);
      acc[1] = MFMA16(a1, bf, acc[1]);
    }
    int col = w * 16 + lr;
    float bias = MNub[col];
    #pragma unroll
    for (int mt = 0; mt < 2; mt++)
      #pragma unroll
      for (int rr = 0; rr < 4; rr++)
        Uf[mt * 16 + lg * 4 + rr][col] = tanh_fast(acc[mt][rr] + bias);
  }
  __syncthreads();
  if (tid < 320) {
    int row = tid / 10, f = tid - (tid / 10) * 10;
    float s = 0.f;
    for (int d = 0; d < 128; d++) s += Uf[row][d] * Rm[f * 128 + d];
    Lg[row][f] = s;
  }
  __syncthreads();
  if (tid < 32) {
    float m = -1e30f;
    #pragma unroll
    for (int f = 0; f < 10; f++) m = fmaxf(m, Lg[tid][f]);
    float e[10], s = 0.f;
    #pragma unroll
    for (int f = 0; f < 10; f++) { e[f] = __expf(Lg[tid][f] - m); s += e[f]; }
    float inv = 1.f / s;
    #pragma unroll
    for (int f = 0; f < 10; f++) Aw[tid][f] = e[f] * inv;
  }
  __syncthreads();
  {
    int row = tid >> 4, d0 = (tid & 15) * 8;
    float a[8] = {0,0,0,0,0,0,0,0};
    for (int f = 0; f < 10; f++) {
      float wgt = Aw[row][f];
      f16x8 mv = *(const f16x8*)(MN + (((size_t)(r0 + row)) * 10 + f) * 128 + d0);
      #pragma unroll
      for (int q = 0; q < 8; q++) a[q] += wgt * (float)mv[q];
    }
    f16x8 o;
    #pragma unroll
    for (int q = 0; q < 8; q++) o[q] = (f16)a[q];
    *(f16x8*)(&ACs[row][d0]) = o;
  }
  __syncthreads();
  // ---- Ut = tanh([y|AC] @ MNu2.T + b) ----
  int mt = w & 1, ntb = (w >> 1) * 4;
  {
    f32x4 acc[4] = {};
    for (int ks = 0; ks < 12; ks++) {
      f16x8 a = (ks < 8)
        ? *(const f16x8*)(&Aty[mt * 16 + lr][ks * 32 + lg * 8])
        : *(const f16x8*)(&ACs[mt * 16 + lr][(ks - 8) * 32 + lg * 8]);
      #pragma unroll
      for (int j = 0; j < 4; j++) {
        f16x8 bf = *(const f16x8*)(MNu2_p + ((size_t)(((ntb + j) * 12 + ks) * 64 + lane) << 3));
        acc[j] = MFMA16(a, bf, acc[j]);
      }
    }
    #pragma unroll
    for (int j = 0; j < 4; j++) {
      int col = (ntb + j) * 16 + lr;
      float bias = MNu2b[col];
      #pragma unroll
      for (int rr = 0; rr < 4; rr++)
        Utl[mt * 16 + lg * 4 + rr][col] = (f16)tanh_fast(acc[j][rr] + bias);
    }
  }
  __syncthreads();
  // ---- y_out = tanh(Ut @ mlp1.T + b); ysum += ----
  {
    f32x4 acc2[4] = {};
    for (int ks = 0; ks < 8; ks++) {
      f16x8 a = *(const f16x8*)(&Utl[mt * 16 + lr][ks * 32 + lg * 8]);
      #pragma unroll
      for (int j = 0; j < 4; j++) {
        f16x8 bf = *(const f16x8*)(mlp1_p + ((size_t)(((ntb + j) * 8 + ks) * 64 + lane) << 3));
        acc2[j] = MFMA16(a, bf, acc2[j]);
      }
    }
    #pragma unroll
    for (int j = 0; j < 4; j++) {
      int col = (ntb + j) * 16 + lr;
      float bias = mlp1b[col];
      #pragma unroll
      for (int rr = 0; rr < 4; rr++) {
        int b = b0 + mt * 16 + lg * 4 + rr;
        atomicAdd(&ysum[(size_t)b * 256 + col], tanh_fast(acc2[j][rr] + bias));
      }
    }
  }
}

// y = ysum/T -> d_out tail (f32) and f16 copy for the scores GEMM
__global__ __launch_bounds__(256) void k_yfin(
    const float* __restrict__ ysum, float* __restrict__ outy, f16* __restrict__ y16)
{
  int i = blockIdx.x * 256 + threadIdx.x;
  float v = ysum[i] * (1.0f / 50.0f);
  outy[i] = v;
  y16[i] = (f16)v;
}

// ============================================================================
// scores GEMM (256 x 100000, K=256), computed twice:
//  pass 0: per-block per-row (max, sumexp) partials; pass 1: write score - lse.
// ============================================================================
template <int FINAL>
__global__ __launch_bounds__(512) void k_scores(
    const f16* __restrict__ y16, const f16* __restrict__ Sy,
    const float* __restrict__ lse, float* __restrict__ pmax,
    float* __restrict__ psum, float* __restrict__ out)
{
  __shared__ __align__(16) char smx[FINAL ? 67584 : 4096];
  int tid = threadIdx.x, w = tid >> 6, lane = tid & 63, lr = lane & 15, lg = lane >> 4;
  int i0 = blockIdx.x * 64;
  int mtb = (w >> 1) * 4, ntb = (w & 1) * 2;
  f32x4 acc[4][2] = {};
  for (int ks = 0; ks < 8; ks++) {
    f16x8 a[4];
    #pragma unroll
    for (int i = 0; i < 4; i++)
      a[i] = *(const f16x8*)(y16 + ((size_t)((mtb + i) * 16 + lr)) * 256 + ks * 32 + lg * 8);
    #pragma unroll
    for (int j = 0; j < 2; j++) {
      int item = i0 + (ntb + j) * 16 + lr;
      int ic = item < NITEMS ? item : (NITEMS - 1);
      f16x8 bv = *(const f16x8*)(Sy + (size_t)ic * 256 + ks * 32 + lg * 8);
      #pragma unroll
      for (int i = 0; i < 4; i++) acc[i][j] = MFMA16(a[i], bv, acc[i][j]);
    }
  }
  if constexpr (!FINAL) {
    float* pm = (float*)smx;            // [2][256]
    float* ps = (float*)(smx + 2048);   // [2][256]
    int item0 = i0 + ntb * 16 + lr, item1 = item0 + 16;
    bool v0 = item0 < NITEMS, v1 = item1 < NITEMS;
    #pragma unroll
    for (int i = 0; i < 4; i++)
      #pragma unroll
      for (int rr = 0; rr < 4; rr++) {
        float x0 = v0 ? acc[i][0][rr] : -1e30f;
        float x1 = v1 ? acc[i][1][rr] : -1e30f;
        float m = fmaxf(x0, x1);
        m = fmaxf(m, __shfl_xor(m, 1)); m = fmaxf(m, __shfl_xor(m, 2));
        m = fmaxf(m, __shfl_xor(m, 4)); m = fmaxf(m, __shfl_xor(m, 8));
        float s = (v0 ? __expf(x0 - m) : 0.f) + (v1 ? __expf(x1 - m) : 0.f);
        s += __shfl_xor(s, 1); s += __shfl_xor(s, 2);
        s += __shfl_xor(s, 4); s += __shfl_xor(s, 8);
        if (lr == 0) {
          int row = (mtb + i) * 16 + lg * 4 + rr;
          pm[(w & 1) * 256 + row] = m;
          ps[(w & 1) * 256 + row] = s;
        }
      }
    __syncthreads();
    if (tid < 256) {
      float m0 = pm[tid], m1 = pm[256 + tid];
      float s0 = ps[tid], s1 = ps[256 + tid];
      float M = fmaxf(m0, m1);
      float S = s0 * __expf(m0 - M) + s1 * __expf(m1 - M);
      pmax[(size_t)tid * 1600 + blockIdx.x] = M;
      psum[(size_t)tid * 1600 + blockIdx.x] = S;
    }
  } else {
    float (*oS)[65] = (float(*)[65])smx;        // [256][65]
    float* lse_s = (float*)(smx + 66560);       // [256]
    if (tid < 256) lse_s[tid] = lse[tid];
    __syncthreads();
    #pragma unroll
    for (int i = 0; i < 4; i++)
      #pragma unroll
      for (int j = 0; j < 2; j++)
        #pragma unroll
        for (int rr = 0; rr < 4; rr++) {
          int row = (mtb + i) * 16 + lg * 4 + rr;
          int c = (ntb + j) * 16 + lr;
          oS[row][c] = acc[i][j][rr] - lse_s[row];
        }
    __syncthreads();
    for (int it = 0; it < 32; it++) {
      int row = it * 8 + (tid >> 6);
      int c = tid & 63;
      if (i0 + c < NITEMS) out[(size_t)row * NITEMS + i0 + c] = oS[row][c];
    }
  }
}

// combine per-block partials -> lse[b]
__global__ __launch_bounds__(256) void k_lse(
    const float* __restrict__ pmax, const float* __restrict__ psum, float* __restrict__ lse)
{
  int b = blockIdx.x, tid = threadIdx.x;
  __shared__ float red[256];
  float m = -1e30f;
  for (int i = tid; i < NBLK4; i += 256) m = fmaxf(m, pmax[(size_t)b * 1600 + i]);
  red[tid] = m; __syncthreads();
  for (int s = 128; s > 0; s >>= 1) {
    if (tid < s) red[tid] = fmaxf(red[tid], red[tid + s]);
    __syncthreads();
  }
  float M = red[0]; __syncthreads();
  float s = 0.f;
  for (int i = tid; i < NBLK4; i += 256)
    s += psum[(size_t)b * 1600 + i] * __expf(pmax[(size_t)b * 1600 + i] - M);
  red[tid] = s; __syncthreads();
  for (int q = 128; q > 0; q >>= 1) {
    if (tid < q) red[tid] += red[tid + q];
    __syncthreads();
  }
  if (tid == 0) lse[b] = M + logf(red[0]);
}

// ============================================================================
extern "C" void kernel_launch(void* const* d_in, const int* in_sizes, int n_in,
                              void* d_out, int out_size, void* d_ws, size_t ws_size,
                              hipStream_t stream) {
  (void)in_sizes; (void)n_in; (void)out_size; (void)ws_size;
  const int*   X     = (const int*)d_in[0];
  const float* E     = (const float*)d_in[1];
  const float* KBE   = (const float*)d_in[2];
  const float* Rm    = (const float*)d_in[3];
  const float* Wih   = (const float*)d_in[4];
  const float* Whh   = (const float*)d_in[5];
  const float* bih   = (const float*)d_in[6];
  const float* bhh   = (const float*)d_in[7];
  const float* MNuW  = (const float*)d_in[8];
  const float* MNub  = (const float*)d_in[9];
  const float* MNu2W = (const float*)d_in[10];
  const float* MNu2b = (const float*)d_in[11];
  const float* MNeaW = (const float*)d_in[12];
  const float* MNeab = (const float*)d_in[13];
  const float* mlp1W = (const float*)d_in[14];
  const float* mlp1b = (const float*)d_in[15];
  const float* mlp2W = (const float*)d_in[16];
  const float* mlp2b = (const float*)d_in[17];

  char* ws = (char*)d_ws;
  f16*   Wih_p  = (f16*)(ws + OFF_WIH);
  f16*   Whh_p  = (f16*)(ws + OFF_WHH);
  f16*   MNu_p  = (f16*)(ws + OFF_MNU);
  f16*   MNu2_p = (f16*)(ws + OFF_MNU2);
  f16*   Wea_p  = (f16*)(ws + OFF_MNEA);
  f16*   mlp1_p = (f16*)(ws + OFF_MLP1);
  f16*   mlp2_p = (f16*)(ws + OFF_MLP2);
  f16*   gi     = (f16*)(ws + OFF_GI);
  f16*   tv     = (f16*)(ws + OFF_TV);
  f16*   MN     = (f16*)(ws + OFF_MN);
  f16*   y_all  = (f16*)(ws + OFF_YALL);
  f16*   Sy     = (f16*)(ws + OFF_SY);
  float* ysum   = (float*)(ws + OFF_YSUM);
  f16*   y16    = (f16*)(ws + OFF_Y16);
  float* pmax   = (float*)(ws + OFF_PMAX);
  float* psum   = (float*)(ws + OFF_PSUM);
  float* lse    = (float*)(ws + OFF_LSE);
  float* outf   = (float*)d_out;

  hipMemsetAsync(ysum, 0, 256 * 256 * sizeof(float), stream);
  k_pack<<<344, 256, 0, stream>>>(Wih, Whh, MNuW, MNu2W, MNeaW, mlp1W, mlp2W, (f16*)ws);
  k_giea_sy<<<3925, 512, 0, stream>>>(X, E, Wih_p, bih, gi, KBE, Wea_p, MNeab, tv,
                                      mlp2_p, mlp2b, Sy);
  k_scan_mn<<<336, 512, 0, stream>>>(Whh_p, bhh, gi, y_all, tv, Rm, MN);
  k_uacut<<<400, 512, 0, stream>>>(y_all, MNu_p, MNub, Rm, MN,
                                   MNu2_p, MNu2b, mlp1_p, mlp1b, ysum);
  k_yfin<<<256, 256, 0, stream>>>(ysum, outf + 25600000, y16);
  k_scores<0><<<NBLK4, 512, 0, stream>>>(y16, Sy, nullptr, pmax, psum, nullptr);
  k_lse<<<256, 256, 0, stream>>>(pmax, psum, lse);
  k_scores<1><<<NBLK4, 512, 0, stream>>>(y16, Sy, lse, nullptr, nullptr, outf);
}

// Round 5
// 374.483 us; speedup vs baseline: 1.4286x; 1.4286x over previous
//
#include <hip/hip_runtime.h>

typedef _Float16 f16;
typedef _Float16 f16x2 __attribute__((ext_vector_type(2)));
typedef _Float16 f16x8 __attribute__((ext_vector_type(8)));
typedef float f32x4 __attribute__((ext_vector_type(4)));

#define MFMA16(a,b,c) __builtin_amdgcn_mfma_f32_16x16x32_f16(a,b,c,0,0,0)

#define NITEMS 100000
#define NBLK4  1563   // ceil(100000/64)

// ---- workspace byte offsets ----
#define OFF_WIH   0u
#define OFF_WHH   393216u
#define OFF_MNU   786432u
#define OFF_MNU2  851968u
#define OFF_MNEA  1048576u
#define OFF_MLP1  1081344u
#define OFF_MLP2  1212416u
#define OFF_GI    1409024u          // 12800x768 f16 (column-rotated layout)
#define OFF_TV    21069824u         // 12800x128 f16
#define OFF_MN    24346624u         // 50x256x10x128 f16
#define OFF_YALL  57114624u         // 12800x256 f16
#define OFF_SY    66945024u         // 100000x256 f16
#define OFF_YSUM  118145024u        // 256x256 f32
#define OFF_Y16   118407168u        // 256x256 f16
#define OFF_PMAX  118538240u        // 256x1600 f32
#define OFF_PSUM  120176640u        // 256x1600 f32
#define OFF_LSE   121815040u        // 256 f32

__device__ __forceinline__ float sigm(float x) { return 1.f / (1.f + __expf(-x)); }
__device__ __forceinline__ float tanh_fast(float x) {
  return 1.f - 2.f / (1.f + __expf(2.f * x));
}
// gi column rotation: bit4 of the within-gate col index moves to bit0
__device__ __forceinline__ int gi_pos(int c) {
  int cg = c & 255;
  return (c & ~255) + ((cg >> 5) << 5) + ((cg & 15) << 1) + ((cg >> 4) & 1);
}

// ============================================================================
// Pack all weight matrices (x @ W.T form) into f16 MFMA B-fragment streams.
// dst[((nt*KS+ks)*64+lane)*8 + j] = W[nt*16 + (lane&15)][ks*32 + (lane>>4)*8 + j]
// ============================================================================
__global__ __launch_bounds__(256) void k_pack(
    const float* s0, const float* s1, const float* s2, const float* s3,
    const float* s4, const float* s5, const float* s6, f16* base)
{
  int fid = blockIdx.x * 256 + threadIdx.x;  // 88064 total
  const float* src; f16* dst; int K, f;
  if (fid < 24576)      { src = s0; dst = base;          K = 256; f = fid; }          // W_ih 768x256
  else if (fid < 49152) { src = s1; dst = base + 196608; K = 256; f = fid - 24576; }  // W_hh 768x256
  else if (fid < 53248) { src = s2; dst = base + 393216; K = 256; f = fid - 49152; }  // MNu_W 128x256
  else if (fid < 65536) { src = s3; dst = base + 425984; K = 384; f = fid - 53248; }  // MNu2_W 256x384
  else if (fid < 67584) { src = s4; dst = base + 524288; K = 128; f = fid - 65536; }  // MNea_W 128x128
  else if (fid < 75776) { src = s5; dst = base + 540672; K = 256; f = fid - 67584; }  // mlp1_W 256x256
  else                  { src = s6; dst = base + 606208; K = 384; f = fid - 75776; }  // mlp2_W 256x384
  int lane = f & 63, t2 = f >> 6, KS = K >> 5;
  int ks = t2 % KS, nt = t2 / KS;
  int row = nt * 16 + (lane & 15), col = ks * 32 + ((lane >> 4) << 3);
  const float* sp = src + (size_t)row * K + col;
  f16x8 v;
  #pragma unroll
  for (int j = 0; j < 8; j++) v[j] = (f16)sp[j];
  *(f16x8*)(dst + (size_t)f * 8) = v;
}

// ============================================================================
//  blocks 0..399    gi = f16(E[X] @ W_ih.T + b_ih)     (column-rotated layout)
//  blocks 400..799  tv = f16(tanh(KBE[X] @ MNea_W.T + b))
// ============================================================================
__global__ __launch_bounds__(512) void k_giea(
    const int* __restrict__ X, const float* __restrict__ E,
    const f16* __restrict__ Wih_p, const float* __restrict__ bih, f16* __restrict__ gi,
    const float* __restrict__ KBE, const f16* __restrict__ Wea_p,
    const float* __restrict__ bea, f16* __restrict__ tv)
{
  __shared__ __align__(16) f16 At[32][264];
  int tid = threadIdx.x;
  int w = tid >> 6, lane = tid & 63, lr = lane & 15, lg = lane >> 4;
  if (blockIdx.x < 400) {
    int r0 = blockIdx.x * 32;         // global row (t*256 + b); one t per block
    int t = r0 >> 8;
    { // stage A-tile (32 rows x 256 K, f32 -> f16), gather with row-0 masking
      int r = tid >> 4, c = (tid & 15) * 16;
      int b = (r0 + r) & 255;
      int item = X[b * 50 + t];
      if (item == 0) {
        #pragma unroll
        for (int j = 0; j < 16; j++) At[r][c + j] = (f16)0.f;
      } else {
        const float4* sp = (const float4*)(E + (size_t)item * 256 + c);
        #pragma unroll
        for (int q = 0; q < 4; q++) {
          float4 v = sp[q];
          At[r][c + q*4 + 0] = (f16)v.x; At[r][c + q*4 + 1] = (f16)v.y;
          At[r][c + q*4 + 2] = (f16)v.z; At[r][c + q*4 + 3] = (f16)v.w;
        }
      }
    }
    __syncthreads();
    f32x4 acc[2][6] = {};
    for (int ks = 0; ks < 8; ks++) {
      f16x8 a0 = *(const f16x8*)(&At[lr][ks * 32 + lg * 8]);
      f16x8 a1 = *(const f16x8*)(&At[16 + lr][ks * 32 + lg * 8]);
      #pragma unroll
      for (int j = 0; j < 6; j++) {
        int nt = w * 6 + j;
        f16x8 bf = *(const f16x8*)(Wih_p + ((size_t)((nt * 8 + ks) * 64 + lane) << 3));
        acc[0][j] = MFMA16(a0, bf, acc[0][j]);
        acc[1][j] = MFMA16(a1, bf, acc[1][j]);
      }
    }
    #pragma unroll
    for (int j = 0; j < 6; j++) {
      int col = (w * 6 + j) * 16 + lr;
      int pos = gi_pos(col);
      float bias = bih[col];
      #pragma unroll
      for (int mt = 0; mt < 2; mt++)
        #pragma unroll
        for (int rr = 0; rr < 4; rr++) {
          int row = r0 + mt * 16 + lg * 4 + rr;
          gi[(size_t)row * 768 + pos] = (f16)(acc[mt][j][rr] + bias);
        }
    }
  } else {
    int r0 = (blockIdx.x - 400) * 32;
    int t = r0 >> 8;
    {
      int r = tid >> 4, c = (tid & 15) * 8;
      int b = (r0 + r) & 255;
      int item = X[b * 50 + t];
      if (item == 0) {
        #pragma unroll
        for (int j = 0; j < 8; j++) At[r][c + j] = (f16)0.f;
      } else {
        const float4* sp = (const float4*)(KBE + (size_t)item * 128 + c);
        #pragma unroll
        for (int q = 0; q < 2; q++) {
          float4 v = sp[q];
          At[r][c + q*4 + 0] = (f16)v.x; At[r][c + q*4 + 1] = (f16)v.y;
          At[r][c + q*4 + 2] = (f16)v.z; At[r][c + q*4 + 3] = (f16)v.w;
        }
      }
    }
    __syncthreads();
    f32x4 acc[2] = {};
    for (int ks = 0; ks < 4; ks++) {
      f16x8 a0 = *(const f16x8*)(&At[lr][ks * 32 + lg * 8]);
      f16x8 a1 = *(const f16x8*)(&At[16 + lr][ks * 32 + lg * 8]);
      f16x8 bf = *(const f16x8*)(Wea_p + ((size_t)((w * 4 + ks) * 64 + lane) << 3));
      acc[0] = MFMA16(a0, bf, acc[0]);
      acc[1] = MFMA16(a1, bf, acc[1]);
    }
    int col = w * 16 + lr;
    float bias = bea[col];
    #pragma unroll
    for (int mt = 0; mt < 2; mt++)
      #pragma unroll
      for (int rr = 0; rr < 4; rr++) {
        int row = r0 + mt * 16 + lg * 4 + rr;
        tv[(size_t)row * 128 + col] = (f16)tanh_fast(acc[mt][rr] + bias);
      }
  }
}

// ============================================================================
// Fused:
//  blocks 0..31    persistent GRU scan, 8 rows each. r-gate W in LDS (131KB);
//                  z/n gate W in VGPRs (4 tiles = 128 regs/lane, 2 waves/SIMD
//                  budget 256 via amdgpu_waves_per_eu(2,2)). Zero per-step
//                  global weight traffic.
//  blocks 32..351  MN trajectory (one wave per (b,f) pair)
//  blocks 352..3476 Sy = tanh([E|KBE] @ mlp2.T + b) over 100k items
// ============================================================================
__global__ __launch_bounds__(512)
__attribute__((amdgpu_waves_per_eu(2, 2)))
void k_fused(
    const f16* __restrict__ Whh_p, const float* __restrict__ bhh,
    const f16* __restrict__ gi, f16* __restrict__ y_all,
    const f16* __restrict__ tv, const float* __restrict__ Rm, f16* __restrict__ MN,
    const float* __restrict__ E, const float* __restrict__ KBE,
    const f16* __restrict__ mlp2_p, const float* __restrict__ mlp2b, f16* __restrict__ Sy)
{
  __shared__ __align__(16) char smem[147456];
  int tid = threadIdx.x, w = tid >> 6, lane = tid & 63, lr = lane & 15, lg = lane >> 4;

  if (blockIdx.x < 32) {
    // ---------------- GRU scan (8 rows/block) ----------------
    f16* Wlds = (f16*)smem;            // r-gate tiles 0..15: 131072 B
    f16* hb0 = (f16*)(smem + 131072);  // [16][256] f16 swizzled, rows 8..15 = 0
    f16* hb1 = (f16*)(smem + 139264);
    int r0 = blockIdx.x * 8;
    {
      const float4* src = (const float4*)Whh_p;
      float4* dst = (float4*)Wlds;
      #pragma unroll
      for (int i = 0; i < 16; i++) dst[tid + i * 512] = src[tid + i * 512];
      float4 z4 = {0.f, 0.f, 0.f, 0.f};
      ((float4*)hb0)[tid] = z4; ((float4*)hb0)[tid + 512] = z4;  // both buffers
    }
    // z/n tiles for this wave's 2 col-tiles, in registers (128 VGPR/lane)
    f16x8 Wz[2][8], Wn[2][8];
    #pragma unroll
    for (int p = 0; p < 2; p++) {
      int tr = 2 * w + p;
      #pragma unroll
      for (int ks = 0; ks < 8; ks++) {
        Wz[p][ks] = *(const f16x8*)(Whh_p + ((size_t)(((16 + tr) * 8 + ks) * 64 + lane) << 3));
        Wn[p][ks] = *(const f16x8*)(Whh_p + ((size_t)(((32 + tr) * 8 + ks) * 64 + lane) << 3));
        asm volatile("" : "+v"(Wz[p][ks]));
        asm volatile("" : "+v"(Wn[p][ks]));
      }
    }
    float bR[2], bZ[2], bN[2];
    #pragma unroll
    for (int p = 0; p < 2; p++) {
      int c = w * 32 + p * 16 + lr;
      bR[p] = bhh[c]; bZ[p] = bhh[c + 256]; bN[p] = bhh[c + 512];
    }
    float hreg[2][4] = {};
    const f16* gP = gi + (size_t)(r0 + lg * 4) * 768 + w * 32 + lr * 2;
    f16x2 P[4][3] = {};
    if (lg < 2) {
      #pragma unroll
      for (int rr = 0; rr < 4; rr++)
        #pragma unroll
        for (int g = 0; g < 3; g++)
          P[rr][g] = *(const f16x2*)(gP + rr * 768 + g * 256);
    }
    __syncthreads();
    f16* hc = hb0; f16* hn_ = hb1;
    int xr = (lr & 7) << 4;
    const f16* wB0 = Wlds + ((size_t)((2 * w) * 8) * 64 + lane) * 8;
    const f16* wB1 = Wlds + ((size_t)((2 * w + 1) * 8) * 64 + lane) * 8;
    for (int t = 0; t < 50; t++) {
      f32x4 aR[2] = {}, aZ[2] = {}, aN[2] = {};
      const char* hbase = (const char*)hc + lr * 512;
      #pragma unroll
      for (int ks = 0; ks < 8; ks++) {
        f16x8 a = *(const f16x8*)(hbase + ((ks * 64 + lg * 16) ^ xr));
        aR[0] = MFMA16(a, *(const f16x8*)(wB0 + ks * 512), aR[0]);
        aR[1] = MFMA16(a, *(const f16x8*)(wB1 + ks * 512), aR[1]);
        aZ[0] = MFMA16(a, Wz[0][ks], aZ[0]);
        aZ[1] = MFMA16(a, Wz[1][ks], aZ[1]);
        aN[0] = MFMA16(a, Wn[0][ks], aN[0]);
        aN[1] = MFMA16(a, Wn[1][ks], aN[1]);
      }
      if (lg < 2) {
        #pragma unroll
        for (int p = 0; p < 2; p++) {
          int col = w * 32 + p * 16 + lr;
          #pragma unroll
          for (int rr = 0; rr < 4; rr++) {
            int row = lg * 4 + rr;                        // 0..7
            float rg = sigm((float)P[rr][0][p] + aR[p][rr] + bR[p]);
            float zg = sigm((float)P[rr][1][p] + aZ[p][rr] + bZ[p]);
            float ng = tanh_fast((float)P[rr][2][p] + rg * (aN[p][rr] + bN[p]));
            float hv = ng + zg * (hreg[p][rr] - ng);
            hreg[p][rr] = hv;
            *(f16*)((char*)hn_ + row * 512 + ((col * 2) ^ ((row & 7) << 4))) = (f16)hv;
          }
        }
        if (t < 49) {
          const f16* gN = gP + (size_t)(t + 1) * 196608;
          #pragma unroll
          for (int rr = 0; rr < 4; rr++)
            #pragma unroll
            for (int g = 0; g < 3; g++)
              P[rr][g] = *(const f16x2*)(gN + rr * 768 + g * 256);
        }
      }
      __syncthreads();
      // vectorized y_all store from the just-written h buffer
      if (tid < 256) {
        int row = tid >> 5, c = tid & 31;
        f16x8 hv = *(const f16x8*)((char*)hn_ + row * 512 + ((c * 16) ^ ((row & 7) << 4)));
        *(f16x8*)(y_all + ((size_t)t * 256 + r0 + row) * 256 + c * 8) = hv;
      }
      f16* tmp = hc; hc = hn_; hn_ = tmp;
    }
  } else if (blockIdx.x < 352) {
    // ---------------- MN trajectory ----------------
    int pair = (blockIdx.x - 32) * 8 + w;   // 2560 pairs
    int b = pair / 10, f = pair - (pair / 10) * 10;
    float r0_ = Rm[f * 128 + lane], r1_ = Rm[f * 128 + 64 + lane];
    float mn0 = 0.f, mn1 = 0.f;
    for (int t = 0; t < 50; t++) {
      size_t base = ((size_t)t * 256 + b) * 128;
      float ea0 = (float)tv[base + lane] + r0_;
      float ea1 = (float)tv[base + 64 + lane] + r1_;
      float p = mn0 * ea0 + mn1 * ea1;
      #pragma unroll
      for (int off = 32; off > 0; off >>= 1) p += __shfl_xor(p, off);
      float g = sigm(p);
      mn0 += (ea0 - mn0) * g;
      mn1 += (ea1 - mn1) * g;
      size_t mb = (((size_t)t * 256 + b) * 10 + f) * 128;
      MN[mb + lane] = (f16)mn0;
      MN[mb + 64 + lane] = (f16)mn1;
    }
  } else {
    // ---------------- Sy ----------------
    f16* At = (f16*)smem;                      // [32][392]
    int i0 = (blockIdx.x - 352) * 32;
    {
      int r = tid >> 4;
      int item = i0 + r;
      f16* rowp = At + r * 392;
      int cE = (tid & 15) * 16, cK = (tid & 15) * 8;
      if (item == 0) {
        #pragma unroll
        for (int j = 0; j < 16; j++) rowp[cE + j] = (f16)0.f;
        #pragma unroll
        for (int j = 0; j < 8; j++) rowp[256 + cK + j] = (f16)0.f;
      } else {
        const float4* sp = (const float4*)(E + (size_t)item * 256 + cE);
        #pragma unroll
        for (int q = 0; q < 4; q++) {
          float4 v = sp[q];
          rowp[cE + q*4 + 0] = (f16)v.x; rowp[cE + q*4 + 1] = (f16)v.y;
          rowp[cE + q*4 + 2] = (f16)v.z; rowp[cE + q*4 + 3] = (f16)v.w;
        }
        const float4* kp = (const float4*)(KBE + (size_t)item * 128 + cK);
        #pragma unroll
        for (int q = 0; q < 2; q++) {
          float4 v = kp[q];
          rowp[256 + cK + q*4 + 0] = (f16)v.x; rowp[256 + cK + q*4 + 1] = (f16)v.y;
          rowp[256 + cK + q*4 + 2] = (f16)v.z; rowp[256 + cK + q*4 + 3] = (f16)v.w;
        }
      }
    }
    __syncthreads();
    int mt = w & 1, nq = w >> 1;               // 8 waves: 2 m-tiles x 4 nt-quads
    f32x4 acc[4] = {};
    for (int ks = 0; ks < 12; ks++) {
      f16x8 a = *(const f16x8*)(&At[(mt * 16 + lr) * 392 + ks * 32 + lg * 8]);
      #pragma unroll
      for (int j = 0; j < 4; j++) {
        int nt = nq * 4 + j;
        f16x8 bf = *(const f16x8*)(mlp2_p + ((size_t)((nt * 12 + ks) * 64 + lane) << 3));
        acc[j] = MFMA16(a, bf, acc[j]);
      }
    }
    #pragma unroll
    for (int j = 0; j < 4; j++) {
      int col = (nq * 4 + j) * 16 + lr;
      float bias = mlp2b[col];
      #pragma unroll
      for (int rr = 0; rr < 4; rr++) {
        int item = i0 + mt * 16 + lg * 4 + rr;
        Sy[(size_t)item * 256 + col] = (f16)tanh_fast(acc[j][rr] + bias);
      }
    }
  }
}

// ============================================================================
// Fused per-(t,b)-tile epilogue:
//  U = tanh(y@MNu.T+b); AW = softmax(U@r.T); AC = sum_f AW*MN (kept in LDS);
//  Ut = tanh([y|AC]@MNu2.T+b); y_out = tanh(Ut@mlp1.T+b); ysum += y_out
// ============================================================================
__global__ __launch_bounds__(512) void k_uacut(
    const f16* __restrict__ y_all, const f16* __restrict__ MNu_p,
    const float* __restrict__ MNub, const float* __restrict__ Rm,
    const f16* __restrict__ MN,
    const f16* __restrict__ MNu2_p, const float* __restrict__ MNu2b,
    const f16* __restrict__ mlp1_p, const float* __restrict__ mlp1b,
    float* __restrict__ ysum)
{
  __shared__ __align__(16) f16 Aty[32][264];
  __shared__ float Uf[32][136];
  __shared__ float Lg[32][10];
  __shared__ float Aw[32][10];
  __shared__ __align__(16) f16 ACs[32][136];
  __shared__ __align__(16) f16 Utl[32][264];
  int tid = threadIdx.x, w = tid >> 6, lane = tid & 63, lr = lane & 15, lg = lane >> 4;
  int r0 = blockIdx.x * 32;
  int b0 = r0 & 255;
  {
    int r = tid >> 4, c = (tid & 15) * 16;
    f16x8 v0 = *(const f16x8*)(y_all + (size_t)(r0 + r) * 256 + c);
    f16x8 v1 = *(const f16x8*)(y_all + (size_t)(r0 + r) * 256 + c + 8);
    *(f16x8*)(&Aty[r][c]) = v0;
    *(f16x8*)(&Aty[r][c + 8]) = v1;
  }
  __syncthreads();
  {
    f32x4 acc[2] = {};
    for (int ks = 0; ks < 8; ks++) {
      f16x8 a0 = *(const f16x8*)(&Aty[lr][ks * 32 + lg * 8]);
      f16x8 a1 = *(const f16x8*)(&Aty[16 + lr][ks * 32 + lg * 8]);
      f16x8 bf = *(const f16x8*)(MNu_p + ((size_t)((w * 8 + ks) * 64 + lane) << 3));
      acc[0] = MFMA16(a0, bf, acc[0]);
      acc[1] = MFMA16(a1, bf, acc[1]);
    }
    int col = w * 16 + lr;
    float bias = MNub[col];
    #pragma unroll
    for (int mt = 0; mt < 2; mt++)
      #pragma unroll
      for (int rr = 0; rr < 4; rr++)
        Uf[mt * 16 + lg * 4 + rr][col] = tanh_fast(acc[mt][rr] + bias);
  }
  __syncthreads();
  if (tid < 320) {
    int row = tid / 10, f = tid - (tid / 10) * 10;
    float s = 0.f;
    for (int d = 0; d < 128; d++) s += Uf[row][d] * Rm[f * 128 + d];
    Lg[row][f] = s;
  }
  __syncthreads();
  if (tid < 32) {
    float m = -1e30f;
    #pragma unroll
    for (int f = 0; f < 10; f++) m = fmaxf(m, Lg[tid][f]);
    float e[10], s = 0.f;
    #pragma unroll
    for (int f = 0; f < 10; f++) { e[f] = __expf(Lg[tid][f] - m); s += e[f]; }
    float inv = 1.f / s;
    #pragma unroll
    for (int f = 0; f < 10; f++) Aw[tid][f] = e[f] * inv;
  }
  __syncthreads();
  {
    int row = tid >> 4, d0 = (tid & 15) * 8;
    float a[8] = {0,0,0,0,0,0,0,0};
    for (int f = 0; f < 10; f++) {
      float wgt = Aw[row][f];
      f16x8 mv = *(const f16x8*)(MN + (((size_t)(r0 + row)) * 10 + f) * 128 + d0);
      #pragma unroll
      for (int q = 0; q < 8; q++) a[q] += wgt * (float)mv[q];
    }
    f16x8 o;
    #pragma unroll
    for (int q = 0; q < 8; q++) o[q] = (f16)a[q];
    *(f16x8*)(&ACs[row][d0]) = o;
  }
  __syncthreads();
  int mt = w & 1, ntb = (w >> 1) * 4;
  {
    f32x4 acc[4] = {};
    for (int ks = 0; ks < 12; ks++) {
      f16x8 a = (ks < 8)
        ? *(const f16x8*)(&Aty[mt * 16 + lr][ks * 32 + lg * 8])
        : *(const f16x8*)(&ACs[mt * 16 + lr][(ks - 8) * 32 + lg * 8]);
      #pragma unroll
      for (int j = 0; j < 4; j++) {
        f16x8 bf = *(const f16x8*)(MNu2_p + ((size_t)(((ntb + j) * 12 + ks) * 64 + lane) << 3));
        acc[j] = MFMA16(a, bf, acc[j]);
      }
    }
    #pragma unroll
    for (int j = 0; j < 4; j++) {
      int col = (ntb + j) * 16 + lr;
      float bias = MNu2b[col];
      #pragma unroll
      for (int rr = 0; rr < 4; rr++)
        Utl[mt * 16 + lg * 4 + rr][col] = (f16)tanh_fast(acc[j][rr] + bias);
    }
  }
  __syncthreads();
  {
    f32x4 acc2[4] = {};
    for (int ks = 0; ks < 8; ks++) {
      f16x8 a = *(const f16x8*)(&Utl[mt * 16 + lr][ks * 32 + lg * 8]);
      #pragma unroll
      for (int j = 0; j < 4; j++) {
        f16x8 bf = *(const f16x8*)(mlp1_p + ((size_t)(((ntb + j) * 8 + ks) * 64 + lane) << 3));
        acc2[j] = MFMA16(a, bf, acc2[j]);
      }
    }
    #pragma unroll
    for (int j = 0; j < 4; j++) {
      int col = (ntb + j) * 16 + lr;
      float bias = mlp1b[col];
      #pragma unroll
      for (int rr = 0; rr < 4; rr++) {
        int b = b0 + mt * 16 + lg * 4 + rr;
        atomicAdd(&ysum[(size_t)b * 256 + col], tanh_fast(acc2[j][rr] + bias));
      }
    }
  }
}

// y = ysum/T -> d_out tail (f32) and f16 copy for the scores GEMM
__global__ __launch_bounds__(256) void k_yfin(
    const float* __restrict__ ysum, float* __restrict__ outy, f16* __restrict__ y16)
{
  int i = blockIdx.x * 256 + threadIdx.x;
  float v = ysum[i] * (1.0f / 50.0f);
  outy[i] = v;
  y16[i] = (f16)v;
}

// ============================================================================
// scores GEMM (256 x 100000, K=256), computed twice:
//  pass 0: per-block per-row (max, sumexp) partials; pass 1: write score - lse.
// ============================================================================
template <int FINAL>
__global__ __launch_bounds__(512) void k_scores(
    const f16* __restrict__ y16, const f16* __restrict__ Sy,
    const float* __restrict__ lse, float* __restrict__ pmax,
    float* __restrict__ psum, float* __restrict__ out)
{
  __shared__ __align__(16) char smx[FINAL ? 67584 : 4096];
  int tid = threadIdx.x, w = tid >> 6, lane = tid & 63, lr = lane & 15, lg = lane >> 4;
  int i0 = blockIdx.x * 64;
  int mtb = (w >> 1) * 4, ntb = (w & 1) * 2;
  f32x4 acc[4][2] = {};
  for (int ks = 0; ks < 8; ks++) {
    f16x8 a[4];
    #pragma unroll
    for (int i = 0; i < 4; i++)
      a[i] = *(const f16x8*)(y16 + ((size_t)((mtb + i) * 16 + lr)) * 256 + ks * 32 + lg * 8);
    #pragma unroll
    for (int j = 0; j < 2; j++) {
      int item = i0 + (ntb + j) * 16 + lr;
      int ic = item < NITEMS ? item : (NITEMS - 1);
      f16x8 bv = *(const f16x8*)(Sy + (size_t)ic * 256 + ks * 32 + lg * 8);
      #pragma unroll
      for (int i = 0; i < 4; i++) acc[i][j] = MFMA16(a[i], bv, acc[i][j]);
    }
  }
  if constexpr (!FINAL) {
    float* pm = (float*)smx;            // [2][256]
    float* ps = (float*)(smx + 2048);   // [2][256]
    int item0 = i0 + ntb * 16 + lr, item1 = item0 + 16;
    bool v0 = item0 < NITEMS, v1 = item1 < NITEMS;
    #pragma unroll
    for (int i = 0; i < 4; i++)
      #pragma unroll
      for (int rr = 0; rr < 4; rr++) {
        float x0 = v0 ? acc[i][0][rr] : -1e30f;
        float x1 = v1 ? acc[i][1][rr] : -1e30f;
        float m = fmaxf(x0, x1);
        m = fmaxf(m, __shfl_xor(m, 1)); m = fmaxf(m, __shfl_xor(m, 2));
        m = fmaxf(m, __shfl_xor(m, 4)); m = fmaxf(m, __shfl_xor(m, 8));
        float s = (v0 ? __expf(x0 - m) : 0.f) + (v1 ? __expf(x1 - m) : 0.f);
        s += __shfl_xor(s, 1); s += __shfl_xor(s, 2);
        s += __shfl_xor(s, 4); s += __shfl_xor(s, 8);
        if (lr == 0) {
          int row = (mtb + i) * 16 + lg * 4 + rr;
          pm[(w & 1) * 256 + row] = m;
          ps[(w & 1) * 256 + row] = s;
        }
      }
    __syncthreads();
    if (tid < 256) {
      float m0 = pm[tid], m1 = pm[256 + tid];
      float s0 = ps[tid], s1 = ps[256 + tid];
      float M = fmaxf(m0, m1);
      float S = s0 * __expf(m0 - M) + s1 * __expf(m1 - M);
      pmax[(size_t)tid * 1600 + blockIdx.x] = M;
      psum[(size_t)tid * 1600 + blockIdx.x] = S;
    }
  } else {
    float (*oS)[65] = (float(*)[65])smx;        // [256][65]
    float* lse_s = (float*)(smx + 66560);       // [256]
    if (tid < 256) lse_s[tid] = lse[tid];
    __syncthreads();
    #pragma unroll
    for (int i = 0; i < 4; i++)
      #pragma unroll
      for (int j = 0; j < 2; j++)
        #pragma unroll
        for (int rr = 0; rr < 4; rr++) {
          int row = (mtb + i) * 16 + lg * 4 + rr;
          int c = (ntb + j) * 16 + lr;
          oS[row][c] = acc[i][j][rr] - lse_s[row];
        }
    __syncthreads();
    for (int it = 0; it < 32; it++) {
      int row = it * 8 + (tid >> 6);
      int c = tid & 63;
      if (i0 + c < NITEMS) out[(size_t)row * NITEMS + i0 + c] = oS[row][c];
    }
  }
}

// combine per-block partials -> lse[b]
__global__ __launch_bounds__(256) void k_lse(
    const float* __restrict__ pmax, const float* __restrict__ psum, float* __restrict__ lse)
{
  int b = blockIdx.x, tid = threadIdx.x;
  __shared__ float red[256];
  float m = -1e30f;
  for (int i = tid; i < NBLK4; i += 256) m = fmaxf(m, pmax[(size_t)b * 1600 + i]);
  red[tid] = m; __syncthreads();
  for (int s = 128; s > 0; s >>= 1) {
    if (tid < s) red[tid] = fmaxf(red[tid], red[tid + s]);
    __syncthreads();
  }
  float M = red[0]; __syncthreads();
  float s = 0.f;
  for (int i = tid; i < NBLK4; i += 256)
    s += psum[(size_t)b * 1600 + i] * __expf(pmax[(size_t)b * 1600 + i] - M);
  red[tid] = s; __syncthreads();
  for (int q = 128; q > 0; q >>= 1) {
    if (tid < q) red[tid] += red[tid + q];
    __syncthreads();
  }
  if (tid == 0) lse[b] = M + logf(red[0]);
}

// ============================================================================
extern "C" void kernel_launch(void* const* d_in, const int* in_sizes, int n_in,
                              void* d_out, int out_size, void* d_ws, size_t ws_size,
                              hipStream_t stream) {
  (void)in_sizes; (void)n_in; (void)out_size; (void)ws_size;
  const int*   X     = (const int*)d_in[0];
  const float* E     = (const float*)d_in[1];
  const float* KBE   = (const float*)d_in[2];
  const float* Rm    = (const float*)d_in[3];
  const float* Wih   = (const float*)d_in[4];
  const float* Whh   = (const float*)d_in[5];
  const float* bih   = (const float*)d_in[6];
  const float* bhh   = (const float*)d_in[7];
  const float* MNuW  = (const float*)d_in[8];
  const float* MNub  = (const float*)d_in[9];
  const float* MNu2W = (const float*)d_in[10];
  const float* MNu2b = (const float*)d_in[11];
  const float* MNeaW = (const float*)d_in[12];
  const float* MNeab = (const float*)d_in[13];
  const float* mlp1W = (const float*)d_in[14];
  const float* mlp1b = (const float*)d_in[15];
  const float* mlp2W = (const float*)d_in[16];
  const float* mlp2b = (const float*)d_in[17];

  char* ws = (char*)d_ws;
  f16*   Wih_p  = (f16*)(ws + OFF_WIH);
  f16*   Whh_p  = (f16*)(ws + OFF_WHH);
  f16*   MNu_p  = (f16*)(ws + OFF_MNU);
  f16*   MNu2_p = (f16*)(ws + OFF_MNU2);
  f16*   Wea_p  = (f16*)(ws + OFF_MNEA);
  f16*   mlp1_p = (f16*)(ws + OFF_MLP1);
  f16*   mlp2_p = (f16*)(ws + OFF_MLP2);
  f16*   gi     = (f16*)(ws + OFF_GI);
  f16*   tv     = (f16*)(ws + OFF_TV);
  f16*   MN     = (f16*)(ws + OFF_MN);
  f16*   y_all  = (f16*)(ws + OFF_YALL);
  f16*   Sy     = (f16*)(ws + OFF_SY);
  float* ysum   = (float*)(ws + OFF_YSUM);
  f16*   y16    = (f16*)(ws + OFF_Y16);
  float* pmax   = (float*)(ws + OFF_PMAX);
  float* psum   = (float*)(ws + OFF_PSUM);
  float* lse    = (float*)(ws + OFF_LSE);
  float* outf   = (float*)d_out;

  hipMemsetAsync(ysum, 0, 256 * 256 * sizeof(float), stream);
  k_pack<<<344, 256, 0, stream>>>(Wih, Whh, MNuW, MNu2W, MNeaW, mlp1W, mlp2W, (f16*)ws);
  k_giea<<<800, 512, 0, stream>>>(X, E, Wih_p, bih, gi, KBE, Wea_p, MNeab, tv);
  k_fused<<<3477, 512, 0, stream>>>(Whh_p, bhh, gi, y_all, tv, Rm, MN,
                                    E, KBE, mlp2_p, mlp2b, Sy);
  k_uacut<<<400, 512, 0, stream>>>(y_all, MNu_p, MNub, Rm, MN,
                                   MNu2_p, MNu2b, mlp1_p, mlp1b, ysum);
  k_yfin<<<256, 256, 0, stream>>>(ysum, outf + 25600000, y16);
  k_scores<0><<<NBLK4, 512, 0, stream>>>(y16, Sy, nullptr, pmax, psum, nullptr);
  k_lse<<<256, 256, 0, stream>>>(pmax, psum, lse);
  k_scores<1><<<NBLK4, 512, 0, stream>>>(y16, Sy, lse, nullptr, nullptr, outf);
}